// Round 4
// baseline (289.124 us; speedup 1.0000x reference)
//
#include <hip/hip_runtime.h>
#include <hip/hip_bf16.h>
#include <hip/hip_fp16.h>

#define NODES 50000
#define NEDGE 800000
#define NPRED 200000

typedef __attribute__((ext_vector_type(8))) short bf16x8;
typedef __attribute__((ext_vector_type(8))) unsigned short u16x8;
typedef __attribute__((ext_vector_type(4))) float f32x4;

__device__ inline float bf2f(unsigned short u) {
    union { unsigned int i; float f; } v; v.i = ((unsigned int)u) << 16; return v.f;
}
__device__ inline unsigned short f2bf(float f) {
    __hip_bfloat16 b = __float2bfloat16(f);
    return *(unsigned short*)&b;
}
__device__ inline float h2f(unsigned short u) {
    __half h = *(__half*)&u; return __half2float(h);
}
__device__ inline unsigned short f2h(float f) {
    __half h = __float2half(f); return *(unsigned short*)&h;
}

// ---------------------------------------------------------------------------
// CSR build: deg count -> 3-phase exclusive scan -> slot fill
// ---------------------------------------------------------------------------
__global__ __launch_bounds__(256) void deg_init(int* __restrict__ deg, int n) {
    int i = blockIdx.x * 256 + threadIdx.x;
    if (i < n) deg[i] = 1;   // deg starts at 1 (self loop)
}

__global__ __launch_bounds__(256) void deg_count4(const int* __restrict__ dstv, int* __restrict__ deg, int E4) {
    int i = blockIdx.x * 256 + threadIdx.x;
    if (i < E4) {
        int4 d4 = ((const int4*)dstv)[i];
        atomicAdd(&deg[d4.x], 1);
        atomicAdd(&deg[d4.y], 1);
        atomicAdd(&deg[d4.z], 1);
        atomicAdd(&deg[d4.w], 1);
    }
}

__global__ __launch_bounds__(256) void scan_bsum(const int* __restrict__ deg, int* __restrict__ bsum, int n) {
    __shared__ int s[256];
    int t = threadIdx.x, b = blockIdx.x;
    int base = b * 1024 + t * 4;
    int sum = 0;
#pragma unroll
    for (int j = 0; j < 4; ++j) { int i = base + j; if (i < n) sum += deg[i] - 1; }
    s[t] = sum; __syncthreads();
    for (int off = 128; off >= 1; off >>= 1) {
        if (t < off) s[t] += s[t + off];
        __syncthreads();
    }
    if (t == 0) bsum[b] = s[0];
}

__global__ void scan_boff(const int* __restrict__ bsum, int* __restrict__ boff, int nb,
                          int* __restrict__ row_ptr, int n) {
    int t = threadIdx.x;           // 64 threads
    int v = (t < nb) ? bsum[t] : 0;
    int orig = v;
    for (int off = 1; off < 64; off <<= 1) {
        int u = __shfl_up(v, off, 64);
        if (t >= off) v += u;
    }
    boff[t] = v - orig;            // exclusive
    if (t == 63) row_ptr[n] = v;   // total = E
}

// writes row_ptr, seeds fillc with row starts, computes dinv
__global__ __launch_bounds__(256) void scan_write(const int* __restrict__ deg, const int* __restrict__ boff,
                                                  int* __restrict__ row_ptr, int* __restrict__ fillc,
                                                  float* __restrict__ dinv, int n) {
    __shared__ int s[256];
    int t = threadIdx.x, b = blockIdx.x;
    int base = b * 1024 + t * 4;
    int v[4]; int sum = 0;
#pragma unroll
    for (int j = 0; j < 4; ++j) { int i = base + j; v[j] = (i < n) ? (deg[i] - 1) : 0; sum += v[j]; }
    s[t] = sum; __syncthreads();
    for (int off = 1; off < 256; off <<= 1) {
        int u = (t >= off) ? s[t - off] : 0;
        __syncthreads();
        s[t] += u;
        __syncthreads();
    }
    int run = s[t] - sum + boff[b];
#pragma unroll
    for (int j = 0; j < 4; ++j) {
        int i = base + j;
        if (i < n) {
            row_ptr[i] = run; fillc[i] = run; run += v[j];
            dinv[i] = rsqrtf((float)deg[i]);
        }
    }
}

__global__ __launch_bounds__(256) void csr_fill(const int* __restrict__ ei,
                                                int* __restrict__ fillc, int* __restrict__ colv, int E) {
    int e = blockIdx.x * 256 + threadIdx.x;
    if (e < E) {
        int s = ei[e];          // src
        int d = ei[E + e];      // dst
        int p = atomicAdd(&fillc[d], 1);
        colv[p] = s;
    }
}

// ---------------------------------------------------------------------------
// Weight permutation into MFMA B-fragment order (bf16).
// B frag for 16x16x32: lane holds B[k][n], n = lane&15, k = (lane>>4)*8 + j.
// pW1 (K=128,N=128), pW2 (K=128,N=64), pWa split into top(k<64)/bot halves,
// each K=64,N=128: index ((h*1024) + (nt*2+kt)*64 + lane)*8 + j.
// ---------------------------------------------------------------------------
__global__ __launch_bounds__(256) void perm_all(const float* __restrict__ W1, const float* __restrict__ W2,
                                                const float* __restrict__ Wa,
                                                unsigned short* __restrict__ pW1,
                                                unsigned short* __restrict__ pW2,
                                                unsigned short* __restrict__ pWa) {
    int t = blockIdx.x * 256 + threadIdx.x;   // 0..5119
    if (t >= 5120) return;
    if (t < 3072) {
        const float* W; unsigned short* P; int N;
        if (t < 2048) { W = W1; P = pW1; N = 128; }
        else          { W = W2; P = pW2; N = 64; t -= 2048; }
        int lane = t & 63;
        int kt = (t >> 6) & 3;
        int nt = t >> 8;
        int n = nt * 16 + (lane & 15);
        int k0 = kt * 32 + (lane >> 4) * 8;
#pragma unroll
        for (int j = 0; j < 8; ++j) P[t * 8 + j] = f2bf(W[(k0 + j) * N + n]);
    } else {
        int tt = t - 3072;                    // 0..2047
        int h = tt >> 10;                     // half: 0 = top (k<64), 1 = bottom
        int r = tt & 1023;
        int lane = r & 63;
        int kt = (r >> 6) & 1;
        int nt = r >> 7;
        int n = nt * 16 + (lane & 15);
        int k0 = h * 64 + kt * 32 + (lane >> 4) * 8;
#pragma unroll
        for (int j = 0; j < 8; ++j) pWa[tt * 8 + j] = f2bf(Wa[(k0 + j) * 128 + n]);
    }
}

// ---------------------------------------------------------------------------
// MFMA GEMM: H[M, NT*16] (bf16) = X[M,128] @ W (pre-permuted bf16 frags).
// One wave = 16 rows, no LDS. A frag = 16B contiguous chunk of a row.
// ---------------------------------------------------------------------------
template <int NT, bool AFP32>
__global__ __launch_bounds__(256) void gemm_mfma(const void* __restrict__ Xv,
                                                 const unsigned short* __restrict__ perm,
                                                 unsigned short* __restrict__ H, int M) {
    int w = blockIdx.x * 4 + (threadIdx.x >> 6);
    int m0 = w * 16;
    if (m0 >= M) return;
    int lane = threadIdx.x & 63;
    int m = lane & 15, q = lane >> 4;
    size_t row = (size_t)(m0 + m);
    bf16x8 a[4];
    if (AFP32) {
        const float* X = (const float*)Xv;
#pragma unroll
        for (int kt = 0; kt < 4; ++kt) {
            float4 f0 = *(const float4*)&X[row * 128 + kt * 32 + q * 8];
            float4 f1 = *(const float4*)&X[row * 128 + kt * 32 + q * 8 + 4];
            bf16x8 av;
            av[0] = (short)f2bf(f0.x); av[1] = (short)f2bf(f0.y);
            av[2] = (short)f2bf(f0.z); av[3] = (short)f2bf(f0.w);
            av[4] = (short)f2bf(f1.x); av[5] = (short)f2bf(f1.y);
            av[6] = (short)f2bf(f1.z); av[7] = (short)f2bf(f1.w);
            a[kt] = av;
        }
    } else {
        const unsigned short* X = (const unsigned short*)Xv;
#pragma unroll
        for (int kt = 0; kt < 4; ++kt)
            a[kt] = *(const bf16x8*)&X[row * 128 + kt * 32 + q * 8];
    }
    const int N = NT * 16;
#pragma unroll
    for (int nt = 0; nt < NT; ++nt) {
        f32x4 c = {0.f, 0.f, 0.f, 0.f};
#pragma unroll
        for (int kt = 0; kt < 4; ++kt) {
            bf16x8 b = *(const bf16x8*)(perm + (size_t)((nt * 4 + kt) * 64 + lane) * 8);
            c = __builtin_amdgcn_mfma_f32_16x16x32_bf16(a[kt], b, c, 0, 0, 0);
        }
#pragma unroll
        for (int r = 0; r < 4; ++r)
            H[(size_t)(m0 + q * 4 + r) * N + nt * 16 + m] = f2bf(c[r]);
    }
}

// ---------------------------------------------------------------------------
// Aggregation (bf16 gathers, fp32 accumulate, unroll-4 ILP):
// out[d] = (sum_{s->d} h[s]*dinv[s] + h[d]*dinv[d]) * dinv[d] + bias
// ---------------------------------------------------------------------------
template <int C, bool RELU>
__global__ __launch_bounds__(256) void agg_bf16(const unsigned short* __restrict__ h,
                                                const int* __restrict__ row_ptr, const int* __restrict__ colv,
                                                const float* __restrict__ dinv, const float* __restrict__ bias,
                                                unsigned short* __restrict__ out) {
    constexpr int TPN = C / 8;          // lanes per node
    constexpr int NPB = 256 / TPN;      // nodes per block
    int d = blockIdx.x * NPB + threadIdx.x / TPN;
    if (d >= NODES) return;
    int c8 = (threadIdx.x % TPN) * 8;
    float dv = dinv[d];
    float acc[8];
    u16x8 self = *(const u16x8*)&h[(size_t)d * C + c8];
#pragma unroll
    for (int j = 0; j < 8; ++j) acc[j] = bf2f(self[j]) * dv;
    int i = row_ptr[d], end = row_ptr[d + 1];
    for (; i + 3 < end; i += 4) {
        int s0 = colv[i], s1 = colv[i + 1], s2 = colv[i + 2], s3 = colv[i + 3];
        float w0 = dinv[s0], w1 = dinv[s1], w2 = dinv[s2], w3 = dinv[s3];
        u16x8 r0 = *(const u16x8*)&h[(size_t)s0 * C + c8];
        u16x8 r1 = *(const u16x8*)&h[(size_t)s1 * C + c8];
        u16x8 r2 = *(const u16x8*)&h[(size_t)s2 * C + c8];
        u16x8 r3 = *(const u16x8*)&h[(size_t)s3 * C + c8];
#pragma unroll
        for (int j = 0; j < 8; ++j)
            acc[j] += bf2f(r0[j]) * w0 + bf2f(r1[j]) * w1 + bf2f(r2[j]) * w2 + bf2f(r3[j]) * w3;
    }
    for (; i < end; ++i) {
        int s0 = colv[i];
        float w0 = dinv[s0];
        u16x8 r0 = *(const u16x8*)&h[(size_t)s0 * C + c8];
#pragma unroll
        for (int j = 0; j < 8; ++j) acc[j] += bf2f(r0[j]) * w0;
    }
    u16x8 ov;
#pragma unroll
    for (int j = 0; j < 8; ++j) {
        float o = acc[j] * dv + bias[c8 + j];
        if (RELU) o = fmaxf(o, 0.f);
        ov[j] = f2bf(o);
    }
    *(u16x8*)&out[(size_t)d * C + c8] = ov;
}

// ---------------------------------------------------------------------------
// uv_gemm: U[n][128] = z[n] @ Wa[0:64,:], V[n][128] = z[n] @ Wa[64:128,:]
// stored fp16. One wave = 16 nodes, K=64 (2 MFMA per 16-col tile).
// ---------------------------------------------------------------------------
__global__ __launch_bounds__(256) void uv_gemm(const unsigned short* __restrict__ zb,
                                               const unsigned short* __restrict__ pWa,
                                               unsigned short* __restrict__ U, unsigned short* __restrict__ V,
                                               int M) {
    int w = blockIdx.x * 4 + (threadIdx.x >> 6);
    int m0 = w * 16;
    if (m0 >= M) return;
    int lane = threadIdx.x & 63;
    int m = lane & 15, q = lane >> 4;
    size_t row = (size_t)(m0 + m);
    bf16x8 a0 = *(const bf16x8*)&zb[row * 64 + q * 8];
    bf16x8 a1 = *(const bf16x8*)&zb[row * 64 + 32 + q * 8];
#pragma unroll
    for (int h = 0; h < 2; ++h) {
        unsigned short* O = h ? V : U;
        const unsigned short* p = pWa + (size_t)h * 1024 * 8;
#pragma unroll
        for (int nt = 0; nt < 8; ++nt) {
            bf16x8 b0 = *(const bf16x8*)(p + (size_t)((nt * 2 + 0) * 64 + lane) * 8);
            bf16x8 b1 = *(const bf16x8*)(p + (size_t)((nt * 2 + 1) * 64 + lane) * 8);
            f32x4 c = {0.f, 0.f, 0.f, 0.f};
            c = __builtin_amdgcn_mfma_f32_16x16x32_bf16(a0, b0, c, 0, 0, 0);
            c = __builtin_amdgcn_mfma_f32_16x16x32_bf16(a1, b1, c, 0, 0, 0);
#pragma unroll
            for (int r = 0; r < 4; ++r)
                O[(size_t)(m0 + q * 4 + r) * 128 + nt * 16 + m] = f2h(c[r]);
        }
    }
}

// ---------------------------------------------------------------------------
// edge_decode: pred[e] = Wb . relu(U[s] + V[d] + ba) + bb
// 32 edges/block, 8 edges/wave, 8 lanes/edge, 16 ch/lane (4x 16B gathers).
// Blocks [0,6250) -> pos, [6250,12500) -> neg.
// ---------------------------------------------------------------------------
__global__ __launch_bounds__(256) void edge_decode(const unsigned short* __restrict__ U,
                                                   const unsigned short* __restrict__ V,
                                                   const int* __restrict__ pos, const int* __restrict__ neg,
                                                   const float* __restrict__ ba, const float* __restrict__ Wb,
                                                   const float* __restrict__ bb, float* __restrict__ out, int P) {
    __shared__ float sba[128], sWb[128];
    int tid = threadIdx.x;
    if (tid < 128) sba[tid] = ba[tid];
    else sWb[tid - 128] = Wb[tid - 128];
    __syncthreads();
    int half = (blockIdx.x >= 6250);
    const int* src = half ? neg : pos;
    float* o = out + (half ? P : 0);
    int b = half ? (int)blockIdx.x - 6250 : (int)blockIdx.x;
    int lane = tid & 63;
    int wv = tid >> 6;
    int e = b * 32 + wv * 8 + (lane >> 3);
    int ch0 = (lane & 7) * 16;
    int s = src[e], d = src[P + e];
    u16x8 u0 = *(const u16x8*)&U[(size_t)s * 128 + ch0];
    u16x8 u1 = *(const u16x8*)&U[(size_t)s * 128 + ch0 + 8];
    u16x8 v0 = *(const u16x8*)&V[(size_t)d * 128 + ch0];
    u16x8 v1 = *(const u16x8*)&V[(size_t)d * 128 + ch0 + 8];
    float acc = 0.f;
#pragma unroll
    for (int j = 0; j < 8; ++j) {
        float a = h2f(u0[j]) + h2f(v0[j]) + sba[ch0 + j];
        acc += fmaxf(a, 0.f) * sWb[ch0 + j];
        float c = h2f(u1[j]) + h2f(v1[j]) + sba[ch0 + 8 + j];
        acc += fmaxf(c, 0.f) * sWb[ch0 + 8 + j];
    }
    acc += __shfl_xor(acc, 1, 64);
    acc += __shfl_xor(acc, 2, 64);
    acc += __shfl_xor(acc, 4, 64);
    if ((lane & 7) == 0) o[e] = acc + bb[0];
}

// ---------------------------------------------------------------------------
extern "C" void kernel_launch(void* const* d_in, const int* in_sizes, int n_in,
                              void* d_out, int out_size, void* d_ws, size_t ws_size,
                              hipStream_t stream) {
    const int N = NODES, E = NEDGE, P = NPRED;
    const float* x  = (const float*)d_in[0];
    const int*   ei = (const int*)d_in[1];
    const int*  pos = (const int*)d_in[2];
    const int*  neg = (const int*)d_in[3];
    const float* W1 = (const float*)d_in[4];
    const float* b1 = (const float*)d_in[5];
    const float* W2 = (const float*)d_in[6];
    const float* b2 = (const float*)d_in[7];
    const float* Wa = (const float*)d_in[8];
    const float* ba = (const float*)d_in[9];
    const float* Wb = (const float*)d_in[10];
    const float* bb = (const float*)d_in[11];
    float* out = (float*)d_out;

    char* w = (char*)d_ws;
    auto alloc = [&](size_t bytes) { char* p = w; w += (bytes + 255) & ~(size_t)255; return p; };
    int*   deg     = (int*)alloc((size_t)N * 4);
    int*   fillc   = (int*)alloc((size_t)N * 4);
    int*   row_ptr = (int*)alloc((size_t)(N + 1) * 4);
    int*   colv    = (int*)alloc((size_t)E * 4);
    float* dinv    = (float*)alloc((size_t)N * 4);
    int*   bsum    = (int*)alloc(64 * 4);
    int*   boff    = (int*)alloc(64 * 4);
    unsigned short* h1b = (unsigned short*)alloc((size_t)N * 128 * 2);  // 12.8 MB
    unsigned short* z1b = (unsigned short*)alloc((size_t)N * 128 * 2);  // 12.8 MB
    unsigned short* h2b = (unsigned short*)alloc((size_t)N * 64 * 2);   // 6.4 MB
    unsigned short* zb  = (unsigned short*)alloc((size_t)N * 64 * 2);   // 6.4 MB
    unsigned short* Ut  = (unsigned short*)alloc((size_t)N * 128 * 2);  // 12.8 MB fp16
    unsigned short* Vt  = (unsigned short*)alloc((size_t)N * 128 * 2);  // 12.8 MB fp16
    unsigned short* pW1 = (unsigned short*)alloc(2048 * 8 * 2);         // 32 KB
    unsigned short* pW2 = (unsigned short*)alloc(1024 * 8 * 2);         // 16 KB
    unsigned short* pWa = (unsigned short*)alloc(2048 * 8 * 2);         // 32 KB

    const int nb = (N + 1023) / 1024;  // 49
    deg_init<<<(N + 255) / 256, 256, 0, stream>>>(deg, N);
    deg_count4<<<(E / 4 + 255) / 256, 256, 0, stream>>>(ei + E, deg, E / 4);
    scan_bsum<<<nb, 256, 0, stream>>>(deg, bsum, N);
    scan_boff<<<1, 64, 0, stream>>>(bsum, boff, nb, row_ptr, N);
    scan_write<<<nb, 256, 0, stream>>>(deg, boff, row_ptr, fillc, dinv, N);
    csr_fill<<<(E + 255) / 256, 256, 0, stream>>>(ei, fillc, colv, E);

    perm_all<<<20, 256, 0, stream>>>(W1, W2, Wa, pW1, pW2, pWa);

    // layer 1: h1 = bf16(x @ W1) ; z1 = bf16(relu(agg(h1) + b1))
    gemm_mfma<8, true><<<782, 256, 0, stream>>>(x, pW1, h1b, N);
    agg_bf16<128, true><<<N / 16, 256, 0, stream>>>(h1b, row_ptr, colv, dinv, b1, z1b);

    // layer 2: h2 = bf16(z1 @ W2) ; z = bf16(agg(h2) + b2)
    gemm_mfma<4, false><<<782, 256, 0, stream>>>(z1b, pW2, h2b, N);
    agg_bf16<64, false><<<(N + 31) / 32, 256, 0, stream>>>(h2b, row_ptr, colv, dinv, b2, zb);

    // decode: per-node u/v tables (fp16), then streaming edge kernel
    uv_gemm<<<782, 256, 0, stream>>>(zb, pWa, Ut, Vt, N);
    edge_decode<<<12500, 256, 0, stream>>>(Ut, Vt, pos, neg, ba, Wb, bb, out, P);
}

// Round 5
// 252.725 us; speedup vs baseline: 1.1440x; 1.1440x over previous
//
#include <hip/hip_runtime.h>
#include <hip/hip_bf16.h>
#include <hip/hip_fp16.h>

#define NODES 50000
#define NEDGE 800000
#define NPRED 200000

typedef __attribute__((ext_vector_type(8))) short bf16x8;
typedef __attribute__((ext_vector_type(8))) unsigned short u16x8;
typedef __attribute__((ext_vector_type(4))) float f32x4;

__device__ inline float bf2f(unsigned short u) {
    union { unsigned int i; float f; } v; v.i = ((unsigned int)u) << 16; return v.f;
}
__device__ inline unsigned short f2bf(float f) {
    __hip_bfloat16 b = __float2bfloat16(f);
    return *(unsigned short*)&b;
}
__device__ inline float h2f(unsigned short u) {
    __half h = *(__half*)&u; return __half2float(h);
}
__device__ inline unsigned short f2h(float f) {
    __half h = __float2half(f); return *(unsigned short*)&h;
}

// ---------------------------------------------------------------------------
// CSR build, single atomic pass:
//   rank_count4: rank[e] = atomicAdd(&cnt[dst[e]], 1)   (cnt -> in-degree)
//   scan(cnt) -> row_ptr ; dinv = rsqrt(cnt+1)
//   csr_fill2: colv[row_ptr[d] + rank[e]] = src[e]      (no atomics)
// ---------------------------------------------------------------------------
__global__ __launch_bounds__(256) void rank_count4(const int* __restrict__ dstv, int* __restrict__ cnt,
                                                   int* __restrict__ rank, int E4) {
    int i = blockIdx.x * 256 + threadIdx.x;
    if (i < E4) {
        int4 d4 = ((const int4*)dstv)[i];
        int4 r4;
        r4.x = atomicAdd(&cnt[d4.x], 1);
        r4.y = atomicAdd(&cnt[d4.y], 1);
        r4.z = atomicAdd(&cnt[d4.z], 1);
        r4.w = atomicAdd(&cnt[d4.w], 1);
        ((int4*)rank)[i] = r4;
    }
}

// phase A: per-block (1024 elems) sums of cnt (in-degree)
__global__ __launch_bounds__(256) void scan_bsum(const int* __restrict__ cnt, int* __restrict__ bsum, int n) {
    __shared__ int s[256];
    int t = threadIdx.x, b = blockIdx.x;
    int base = b * 1024 + t * 4;
    int sum = 0;
#pragma unroll
    for (int j = 0; j < 4; ++j) { int i = base + j; if (i < n) sum += cnt[i]; }
    s[t] = sum; __syncthreads();
    for (int off = 128; off >= 1; off >>= 1) {
        if (t < off) s[t] += s[t + off];
        __syncthreads();
    }
    if (t == 0) bsum[b] = s[0];
}

__global__ void scan_boff(const int* __restrict__ bsum, int* __restrict__ boff, int nb,
                          int* __restrict__ row_ptr, int n) {
    int t = threadIdx.x;           // 64 threads
    int v = (t < nb) ? bsum[t] : 0;
    int orig = v;
    for (int off = 1; off < 64; off <<= 1) {
        int u = __shfl_up(v, off, 64);
        if (t >= off) v += u;
    }
    boff[t] = v - orig;            // exclusive
    if (t == 63) row_ptr[n] = v;   // total = E
}

__global__ __launch_bounds__(256) void scan_write(const int* __restrict__ cnt, const int* __restrict__ boff,
                                                  int* __restrict__ row_ptr, float* __restrict__ dinv, int n) {
    __shared__ int s[256];
    int t = threadIdx.x, b = blockIdx.x;
    int base = b * 1024 + t * 4;
    int v[4]; int sum = 0;
#pragma unroll
    for (int j = 0; j < 4; ++j) { int i = base + j; v[j] = (i < n) ? cnt[i] : 0; sum += v[j]; }
    s[t] = sum; __syncthreads();
    for (int off = 1; off < 256; off <<= 1) {
        int u = (t >= off) ? s[t - off] : 0;
        __syncthreads();
        s[t] += u;
        __syncthreads();
    }
    int run = s[t] - sum + boff[b];
#pragma unroll
    for (int j = 0; j < 4; ++j) {
        int i = base + j;
        if (i < n) {
            row_ptr[i] = run; run += v[j];
            dinv[i] = rsqrtf((float)(v[j] + 1));   // +1 self loop
        }
    }
}

__global__ __launch_bounds__(256) void csr_fill2(const int* __restrict__ ei, const int* __restrict__ rank,
                                                 const int* __restrict__ row_ptr, int* __restrict__ colv, int E4) {
    int i = blockIdx.x * 256 + threadIdx.x;
    if (i < E4) {
        int4 s4 = ((const int4*)ei)[i];
        int4 d4 = ((const int4*)(ei + NEDGE))[i];
        int4 r4 = ((const int4*)rank)[i];
        colv[row_ptr[d4.x] + r4.x] = s4.x;
        colv[row_ptr[d4.y] + r4.y] = s4.y;
        colv[row_ptr[d4.z] + r4.z] = s4.z;
        colv[row_ptr[d4.w] + r4.w] = s4.w;
    }
}

// ---------------------------------------------------------------------------
// Weight permutation into MFMA B-fragment order (bf16).
// B frag for 16x16x32: lane holds B[k][n], n = lane&15, k = (lane>>4)*8 + j.
// pW1 (K=128,N=128), pW2 (K=128,N=64), pWa split into top(k<64)/bot halves,
// each K=64,N=128: index ((h*1024) + (nt*2+kt)*64 + lane)*8 + j.
// ---------------------------------------------------------------------------
__global__ __launch_bounds__(256) void perm_all(const float* __restrict__ W1, const float* __restrict__ W2,
                                                const float* __restrict__ Wa,
                                                unsigned short* __restrict__ pW1,
                                                unsigned short* __restrict__ pW2,
                                                unsigned short* __restrict__ pWa) {
    int t = blockIdx.x * 256 + threadIdx.x;   // 0..5119
    if (t >= 5120) return;
    if (t < 3072) {
        const float* W; unsigned short* P; int N;
        if (t < 2048) { W = W1; P = pW1; N = 128; }
        else          { W = W2; P = pW2; N = 64; t -= 2048; }
        int lane = t & 63;
        int kt = (t >> 6) & 3;
        int nt = t >> 8;
        int n = nt * 16 + (lane & 15);
        int k0 = kt * 32 + (lane >> 4) * 8;
#pragma unroll
        for (int j = 0; j < 8; ++j) P[t * 8 + j] = f2bf(W[(k0 + j) * N + n]);
    } else {
        int tt = t - 3072;                    // 0..2047
        int h = tt >> 10;                     // half: 0 = top (k<64), 1 = bottom
        int r = tt & 1023;
        int lane = r & 63;
        int kt = (r >> 6) & 1;
        int nt = r >> 7;
        int n = nt * 16 + (lane & 15);
        int k0 = h * 64 + kt * 32 + (lane >> 4) * 8;
#pragma unroll
        for (int j = 0; j < 8; ++j) pWa[tt * 8 + j] = f2bf(Wa[(k0 + j) * 128 + n]);
    }
}

// ---------------------------------------------------------------------------
// MFMA GEMM: H[M, NT*16] (bf16) = X[M,128] @ W (pre-permuted bf16 frags).
// One wave = 16 rows, no LDS. A frag = 16B contiguous chunk of a row.
// ---------------------------------------------------------------------------
template <int NT, bool AFP32>
__global__ __launch_bounds__(256) void gemm_mfma(const void* __restrict__ Xv,
                                                 const unsigned short* __restrict__ perm,
                                                 unsigned short* __restrict__ H, int M) {
    int w = blockIdx.x * 4 + (threadIdx.x >> 6);
    int m0 = w * 16;
    if (m0 >= M) return;
    int lane = threadIdx.x & 63;
    int m = lane & 15, q = lane >> 4;
    size_t row = (size_t)(m0 + m);
    bf16x8 a[4];
    if (AFP32) {
        const float* X = (const float*)Xv;
#pragma unroll
        for (int kt = 0; kt < 4; ++kt) {
            float4 f0 = *(const float4*)&X[row * 128 + kt * 32 + q * 8];
            float4 f1 = *(const float4*)&X[row * 128 + kt * 32 + q * 8 + 4];
            bf16x8 av;
            av[0] = (short)f2bf(f0.x); av[1] = (short)f2bf(f0.y);
            av[2] = (short)f2bf(f0.z); av[3] = (short)f2bf(f0.w);
            av[4] = (short)f2bf(f1.x); av[5] = (short)f2bf(f1.y);
            av[6] = (short)f2bf(f1.z); av[7] = (short)f2bf(f1.w);
            a[kt] = av;
        }
    } else {
        const unsigned short* X = (const unsigned short*)Xv;
#pragma unroll
        for (int kt = 0; kt < 4; ++kt)
            a[kt] = *(const bf16x8*)&X[row * 128 + kt * 32 + q * 8];
    }
    const int N = NT * 16;
#pragma unroll
    for (int nt = 0; nt < NT; ++nt) {
        f32x4 c = {0.f, 0.f, 0.f, 0.f};
#pragma unroll
        for (int kt = 0; kt < 4; ++kt) {
            bf16x8 b = *(const bf16x8*)(perm + (size_t)((nt * 4 + kt) * 64 + lane) * 8);
            c = __builtin_amdgcn_mfma_f32_16x16x32_bf16(a[kt], b, c, 0, 0, 0);
        }
#pragma unroll
        for (int r = 0; r < 4; ++r)
            H[(size_t)(m0 + q * 4 + r) * N + nt * 16 + m] = f2bf(c[r]);
    }
}

// ---------------------------------------------------------------------------
// Aggregation (bf16 gathers, fp32 accumulate, unroll-4 ILP):
// out[d] = (sum_{s->d} h[s]*dinv[s] + h[d]*dinv[d]) * dinv[d] + bias
// ---------------------------------------------------------------------------
template <int C, bool RELU>
__global__ __launch_bounds__(256) void agg_bf16(const unsigned short* __restrict__ h,
                                                const int* __restrict__ row_ptr, const int* __restrict__ colv,
                                                const float* __restrict__ dinv, const float* __restrict__ bias,
                                                unsigned short* __restrict__ out) {
    constexpr int TPN = C / 8;          // lanes per node
    constexpr int NPB = 256 / TPN;      // nodes per block
    int d = blockIdx.x * NPB + threadIdx.x / TPN;
    if (d >= NODES) return;
    int c8 = (threadIdx.x % TPN) * 8;
    float dv = dinv[d];
    float acc[8];
    u16x8 self = *(const u16x8*)&h[(size_t)d * C + c8];
#pragma unroll
    for (int j = 0; j < 8; ++j) acc[j] = bf2f(self[j]) * dv;
    int i = row_ptr[d], end = row_ptr[d + 1];
    for (; i + 3 < end; i += 4) {
        int s0 = colv[i], s1 = colv[i + 1], s2 = colv[i + 2], s3 = colv[i + 3];
        float w0 = dinv[s0], w1 = dinv[s1], w2 = dinv[s2], w3 = dinv[s3];
        u16x8 r0 = *(const u16x8*)&h[(size_t)s0 * C + c8];
        u16x8 r1 = *(const u16x8*)&h[(size_t)s1 * C + c8];
        u16x8 r2 = *(const u16x8*)&h[(size_t)s2 * C + c8];
        u16x8 r3 = *(const u16x8*)&h[(size_t)s3 * C + c8];
#pragma unroll
        for (int j = 0; j < 8; ++j)
            acc[j] += bf2f(r0[j]) * w0 + bf2f(r1[j]) * w1 + bf2f(r2[j]) * w2 + bf2f(r3[j]) * w3;
    }
    for (; i < end; ++i) {
        int s0 = colv[i];
        float w0 = dinv[s0];
        u16x8 r0 = *(const u16x8*)&h[(size_t)s0 * C + c8];
#pragma unroll
        for (int j = 0; j < 8; ++j) acc[j] += bf2f(r0[j]) * w0;
    }
    u16x8 ov;
#pragma unroll
    for (int j = 0; j < 8; ++j) {
        float o = acc[j] * dv + bias[c8 + j];
        if (RELU) o = fmaxf(o, 0.f);
        ov[j] = f2bf(o);
    }
    *(u16x8*)&out[(size_t)d * C + c8] = ov;
}

// ---------------------------------------------------------------------------
// uv_gemm: U[n][128] = z[n] @ Wa[0:64,:], V[n][128] = z[n] @ Wa[64:128,:]
// stored fp16. One wave = 16 nodes, K=64 (2 MFMA per 16-col tile).
// ---------------------------------------------------------------------------
__global__ __launch_bounds__(256) void uv_gemm(const unsigned short* __restrict__ zb,
                                               const unsigned short* __restrict__ pWa,
                                               unsigned short* __restrict__ U, unsigned short* __restrict__ V,
                                               int M) {
    int w = blockIdx.x * 4 + (threadIdx.x >> 6);
    int m0 = w * 16;
    if (m0 >= M) return;
    int lane = threadIdx.x & 63;
    int m = lane & 15, q = lane >> 4;
    size_t row = (size_t)(m0 + m);
    bf16x8 a0 = *(const bf16x8*)&zb[row * 64 + q * 8];
    bf16x8 a1 = *(const bf16x8*)&zb[row * 64 + 32 + q * 8];
#pragma unroll
    for (int h = 0; h < 2; ++h) {
        unsigned short* O = h ? V : U;
        const unsigned short* p = pWa + (size_t)h * 1024 * 8;
#pragma unroll
        for (int nt = 0; nt < 8; ++nt) {
            bf16x8 b0 = *(const bf16x8*)(p + (size_t)((nt * 2 + 0) * 64 + lane) * 8);
            bf16x8 b1 = *(const bf16x8*)(p + (size_t)((nt * 2 + 1) * 64 + lane) * 8);
            f32x4 c = {0.f, 0.f, 0.f, 0.f};
            c = __builtin_amdgcn_mfma_f32_16x16x32_bf16(a0, b0, c, 0, 0, 0);
            c = __builtin_amdgcn_mfma_f32_16x16x32_bf16(a1, b1, c, 0, 0, 0);
#pragma unroll
            for (int r = 0; r < 4; ++r)
                O[(size_t)(m0 + q * 4 + r) * 128 + nt * 16 + m] = f2h(c[r]);
        }
    }
}

// ---------------------------------------------------------------------------
// edge_decode2: pred[e] = Wb . relu(U[s] + V[d] + ba) + bb
// 128 edges/block; 8-lane group handles 4 edges; all 16 gathers issued
// before consumption (agg-style MLP). No LDS, no barrier.
// out[ge] for ge in [0,2P): first P = pos, second P = neg.
// ---------------------------------------------------------------------------
__global__ __launch_bounds__(256) void edge_decode2(const unsigned short* __restrict__ U,
                                                    const unsigned short* __restrict__ V,
                                                    const int* __restrict__ pos, const int* __restrict__ neg,
                                                    const float* __restrict__ ba, const float* __restrict__ Wb,
                                                    const float* __restrict__ bb, float* __restrict__ out, int P) {
    int tid = threadIdx.x;
    int grp = tid >> 3;                 // 0..31 lane-groups per block
    int ch0 = (tid & 7) * 16;
    float bav[16], wbv[16];
    *(float4*)&bav[0]  = *(const float4*)&ba[ch0];
    *(float4*)&bav[4]  = *(const float4*)&ba[ch0 + 4];
    *(float4*)&bav[8]  = *(const float4*)&ba[ch0 + 8];
    *(float4*)&bav[12] = *(const float4*)&ba[ch0 + 12];
    *(float4*)&wbv[0]  = *(const float4*)&Wb[ch0];
    *(float4*)&wbv[4]  = *(const float4*)&Wb[ch0 + 4];
    *(float4*)&wbv[8]  = *(const float4*)&Wb[ch0 + 8];
    *(float4*)&wbv[12] = *(const float4*)&Wb[ch0 + 12];
    int e0 = blockIdx.x * 128 + grp * 4;     // 4 contiguous edges (same half: P%4==0)
    int half = (e0 >= P);
    const int* src = half ? neg : pos;
    int le0 = half ? e0 - P : e0;
    int s[4], d[4];
#pragma unroll
    for (int j = 0; j < 4; ++j) { s[j] = src[le0 + j]; d[j] = src[P + le0 + j]; }
    u16x8 u0[4], u1[4], v0[4], v1[4];
#pragma unroll
    for (int j = 0; j < 4; ++j) {
        u0[j] = *(const u16x8*)&U[(size_t)s[j] * 128 + ch0];
        u1[j] = *(const u16x8*)&U[(size_t)s[j] * 128 + ch0 + 8];
        v0[j] = *(const u16x8*)&V[(size_t)d[j] * 128 + ch0];
        v1[j] = *(const u16x8*)&V[(size_t)d[j] * 128 + ch0 + 8];
    }
    float acc[4];
#pragma unroll
    for (int j = 0; j < 4; ++j) {
        float a = 0.f;
#pragma unroll
        for (int k = 0; k < 8; ++k) {
            float h0 = h2f((unsigned short)u0[j][k]) + h2f((unsigned short)v0[j][k]) + bav[k];
            a += fmaxf(h0, 0.f) * wbv[k];
            float h1 = h2f((unsigned short)u1[j][k]) + h2f((unsigned short)v1[j][k]) + bav[8 + k];
            a += fmaxf(h1, 0.f) * wbv[8 + k];
        }
        acc[j] = a;
    }
#pragma unroll
    for (int off = 1; off <= 4; off <<= 1) {
#pragma unroll
        for (int j = 0; j < 4; ++j) acc[j] += __shfl_xor(acc[j], off, 64);
    }
    if ((tid & 7) == 0) {
        float bbv = bb[0];
        float4 st = { acc[0] + bbv, acc[1] + bbv, acc[2] + bbv, acc[3] + bbv };
        *(float4*)&out[e0] = st;
    }
}

// ---------------------------------------------------------------------------
extern "C" void kernel_launch(void* const* d_in, const int* in_sizes, int n_in,
                              void* d_out, int out_size, void* d_ws, size_t ws_size,
                              hipStream_t stream) {
    const int N = NODES, E = NEDGE, P = NPRED;
    const float* x  = (const float*)d_in[0];
    const int*   ei = (const int*)d_in[1];
    const int*  pos = (const int*)d_in[2];
    const int*  neg = (const int*)d_in[3];
    const float* W1 = (const float*)d_in[4];
    const float* b1 = (const float*)d_in[5];
    const float* W2 = (const float*)d_in[6];
    const float* b2 = (const float*)d_in[7];
    const float* Wa = (const float*)d_in[8];
    const float* ba = (const float*)d_in[9];
    const float* Wb = (const float*)d_in[10];
    const float* bb = (const float*)d_in[11];
    float* out = (float*)d_out;

    char* w = (char*)d_ws;
    auto alloc = [&](size_t bytes) { char* p = w; w += (bytes + 255) & ~(size_t)255; return p; };
    int*   cnt     = (int*)alloc((size_t)N * 4);
    int*   rankb   = (int*)alloc((size_t)E * 4);
    int*   row_ptr = (int*)alloc((size_t)(N + 1) * 4);
    int*   colv    = (int*)alloc((size_t)E * 4);
    float* dinv    = (float*)alloc((size_t)N * 4);
    int*   bsum    = (int*)alloc(64 * 4);
    int*   boff    = (int*)alloc(64 * 4);
    unsigned short* h1b = (unsigned short*)alloc((size_t)N * 128 * 2);  // 12.8 MB
    unsigned short* z1b = (unsigned short*)alloc((size_t)N * 128 * 2);  // 12.8 MB
    unsigned short* h2b = (unsigned short*)alloc((size_t)N * 64 * 2);   // 6.4 MB
    unsigned short* zb  = (unsigned short*)alloc((size_t)N * 64 * 2);   // 6.4 MB
    unsigned short* Ut  = (unsigned short*)alloc((size_t)N * 128 * 2);  // 12.8 MB fp16
    unsigned short* Vt  = (unsigned short*)alloc((size_t)N * 128 * 2);  // 12.8 MB fp16
    unsigned short* pW1 = (unsigned short*)alloc(2048 * 8 * 2);         // 32 KB
    unsigned short* pW2 = (unsigned short*)alloc(1024 * 8 * 2);         // 16 KB
    unsigned short* pWa = (unsigned short*)alloc(2048 * 8 * 2);         // 32 KB

    const int nb = (N + 1023) / 1024;  // 49
    hipMemsetAsync(cnt, 0, (size_t)N * 4, stream);
    rank_count4<<<(E / 4 + 255) / 256, 256, 0, stream>>>(ei + E, cnt, rankb, E / 4);
    scan_bsum<<<nb, 256, 0, stream>>>(cnt, bsum, N);
    scan_boff<<<1, 64, 0, stream>>>(bsum, boff, nb, row_ptr, N);
    scan_write<<<nb, 256, 0, stream>>>(cnt, boff, row_ptr, dinv, N);
    csr_fill2<<<(E / 4 + 255) / 256, 256, 0, stream>>>(ei, rankb, row_ptr, colv, E / 4);

    perm_all<<<20, 256, 0, stream>>>(W1, W2, Wa, pW1, pW2, pWa);

    // layer 1: h1 = bf16(x @ W1) ; z1 = bf16(relu(agg(h1) + b1))
    gemm_mfma<8, true><<<782, 256, 0, stream>>>(x, pW1, h1b, N);
    agg_bf16<128, true><<<N / 16, 256, 0, stream>>>(h1b, row_ptr, colv, dinv, b1, z1b);

    // layer 2: h2 = bf16(z1 @ W2) ; z = bf16(agg(h2) + b2)
    gemm_mfma<4, false><<<782, 256, 0, stream>>>(z1b, pW2, h2b, N);
    agg_bf16<64, false><<<(N + 31) / 32, 256, 0, stream>>>(h2b, row_ptr, colv, dinv, b2, zb);

    // decode: per-node u/v tables (fp16), then streaming edge kernel
    uv_gemm<<<782, 256, 0, stream>>>(zb, pWa, Ut, Vt, N);
    edge_decode2<<<(2 * P) / 128, 256, 0, stream>>>(Ut, Vt, pos, neg, ba, Wb, bb, out, P);
}